// Round 15
// baseline (165.139 us; speedup 1.0000x reference)
//
#include <hip/hip_runtime.h>
#include <hip/hip_bf16.h>
#include <cstdint>

// LSTM cell: B=8192, D=1024, U=1024.
// z = [X|H](8192x2048) @ Wcat(2048x4096), gate interleave 16 in N, fused epilogue.
// GEMM: 256x256 tile, BK=32, 8 waves (4Mx2N), wave tile 64x128.
// ZERO LDS, ZERO barriers: both operands pre-packed FRAGMENT-MAJOR in workspace;
// per window each wave issues 12 coalesced global_load_dwordx4 (4 A + 8 B frags,
// p/q double-buffered 1 window ahead) + 32 MFMA. Compiler-managed vmcnt.
// Same-address redundancy across mate-waves (A x2, B x4) served by L1/L2.

using f32x4  = __attribute__((ext_vector_type(4))) float;
using short8 = __attribute__((ext_vector_type(8))) short;

__device__ __forceinline__ unsigned short f2bf(float f) {
  union { float f; unsigned int u; } v; v.f = f;
  unsigned int r = v.u + 0x7fffu + ((v.u >> 16) & 1u);  // RNE
  return (unsigned short)(r >> 16);
}
__device__ __forceinline__ float sigmoidf_fast(float x) { return 1.f / (1.f + __expf(-x)); }
__device__ __forceinline__ float tanhf_fast(float x)    { return 1.f - 2.f / (__expf(2.f * x) + 1.f); }

// ---------- A conversion: fragment-major A' (same as R14, verified).
// A'[((bm*64+kt)*16+f)*512 + l*8 + e] = bf16(src[bm*256+f*16+(l&15)][kt*32+(l>>4)*8+e])
__global__ void conv_a_kernel(const float* __restrict__ X, const float* __restrict__ H,
                              unsigned short* __restrict__ Ap) {
  __shared__ float tile[256][36];
  int kt = blockIdx.x;       // 0..63
  int bm = blockIdx.y;       // 0..31
  const float* src = (kt < 32) ? X : H;
  int kbase = (kt & 31) * 32;
  int t = threadIdx.x;
#pragma unroll
  for (int i = 0; i < 8; ++i) {
    int flat = i * 256 + t;          // 0..2047
    int row = flat >> 3;             // 0..255
    int kq  = (flat & 7) * 4;
    float4 v = *(const float4*)(src + (long)(bm * 256 + row) * 1024 + kbase + kq);
    tile[row][kq]     = v.x; tile[row][kq + 1] = v.y;
    tile[row][kq + 2] = v.z; tile[row][kq + 3] = v.w;
  }
  __syncthreads();
  long obase = (long)(bm * 64 + kt) * 8192;   // 16 frags * 512 elems
#pragma unroll
  for (int i = 0; i < 4; ++i) {
    int p = i * 256 + t;             // (f,l) pair, 0..1023
    int f = p >> 6, l = p & 63;
    int row = f * 16 + (l & 15);
    int kc  = (l >> 4) * 8;
    float4 v0 = *(const float4*)&tile[row][kc];
    float4 v1 = *(const float4*)&tile[row][kc + 4];
    unsigned short ov[8];
    ov[0] = f2bf(v0.x); ov[1] = f2bf(v0.y); ov[2] = f2bf(v0.z); ov[3] = f2bf(v0.w);
    ov[4] = f2bf(v1.x); ov[5] = f2bf(v1.y); ov[6] = f2bf(v1.z); ov[7] = f2bf(v1.w);
    *(uint4*)(Ap + obase + (long)p * 8) = *(uint4*)ov;
  }
}

// ---------- B conversion: fragment-major B', gate interleave 16.
// Global col n = (u>>4)*64 + g*16 + (u&15). Element (n,k) ->
// Bp[((bn*64+kt)*16+f)*512 + l*8 + e], bn=n>>8, f=(n>>4)&15,
// l=(n&15)+16*((k>>3)&3), kt=k>>5, e=k&7.
__global__ void conv_b_kernel(const float* W_i, const float* U_i,
                              const float* W_f, const float* U_f,
                              const float* W_c, const float* U_c,
                              const float* W_o, const float* U_o,
                              unsigned short* __restrict__ Bp) {
  __shared__ float tile[64][65];
  int z = blockIdx.z;
  const float* src;
  switch (z) {
    case 0: src = W_i; break; case 1: src = U_i; break;
    case 2: src = W_f; break; case 3: src = U_f; break;
    case 4: src = W_c; break; case 5: src = U_c; break;
    case 6: src = W_o; break; default: src = U_o; break;
  }
  int g = z >> 1, s = z & 1;
  int k0 = blockIdx.x * 64;
  int u0 = blockIdx.y * 64;
  int t = threadIdx.x;
  int c = t & 63, r0 = t >> 6;
#pragma unroll
  for (int i = 0; i < 16; ++i) {
    int r = i * 4 + r0;
    tile[r][c] = src[(long)(k0 + r) * 1024 + u0 + c];
  }
  __syncthreads();
  int ul = t >> 2;
  int ks = (t & 3) * 16;
  unsigned short outv[16];
#pragma unroll
  for (int j = 0; j < 16; ++j) outv[j] = f2bf(tile[ks + j][ul]);
  int u = u0 + ul;
  long n   = 4L * (u >> 4) * 16 + (long)(u >> 4) * 0 + ((long)(u >> 4) * 64) + g * 16 + (u & 15);
  n = ((long)(u >> 4)) * 64 + g * 16 + (u & 15);       // gate interleave 16
  long col = (long)s * 1024 + k0 + ks;                 // 16-aligned
  int kt = (int)(col >> 5);
  int bnb = (int)(n >> 8);
  int f   = (int)((n >> 4) & 15);
  int l0  = (int)((n & 15) + (((col >> 3) & 3) << 4)); // in {0..15} u {32..47}
  long base = ((long)(bnb * 64 + kt) * 16 + f) * 512;
  *(uint4*)(Bp + base + (long)l0 * 8)        = *(uint4*)(outv);
  *(uint4*)(Bp + base + (long)(l0 + 16) * 8) = *(uint4*)(outv + 8);
}

// ---------- fused GEMM + LSTM epilogue (no LDS, no barriers)
__global__ __launch_bounds__(512, 2) void lstm_gemm_kernel(
    const unsigned short* __restrict__ Ap,    // fragment-major A'
    const unsigned short* __restrict__ Bp,    // fragment-major B'
    const float* __restrict__ b_i, const float* __restrict__ b_f,
    const float* __restrict__ b_c, const float* __restrict__ b_o,
    const float* __restrict__ c_tm1,
    float* __restrict__ outH, float* __restrict__ outC) {
  int bid = blockIdx.x;
  int swz = (bid & 7) * 64 + (bid >> 3);  // XCD swizzle, 512 % 8 == 0
  int bm = swz >> 4;   // 32 m-blocks
  int bn = swz & 15;   // 16 n-blocks

  int t = threadIdx.x;
  int lane = t & 63;
  int w = t >> 6;           // 8 waves
  int wm = w >> 1;          // 0..3 (M quarter, 64 rows)
  int wn = w & 1;           // 0..1 (N half, 128 cols = frags wn*8..wn*8+7)
  int rl = lane & 15;
  int kg = lane >> 4;

  // frag mi of window kt: gA + kt*8192 + mi*512; frag ni: gB + kt*8192 + ni*512
  const unsigned short* gA = Ap + ((long)bm * 64 * 16 + wm * 4) * 512 + lane * 8;
  const unsigned short* gB = Bp + ((long)bn * 64 * 16 + wn * 8) * 512 + lane * 8;

  f32x4 acc[4][8];
#pragma unroll
  for (int mi = 0; mi < 4; ++mi)
#pragma unroll
    for (int ni = 0; ni < 8; ++ni) acc[mi][ni] = (f32x4){0.f, 0.f, 0.f, 0.f};

  short8 pa0, pa1, pa2, pa3, pb0, pb1, pb2, pb3, pb4, pb5, pb6, pb7;
  short8 qa0, qa1, qa2, qa3, qb0, qb1, qb2, qb3, qb4, qb5, qb6, qb7;

#define LOADSET(S, KO)                                                         \
  do {                                                                         \
    S##a0 = *(const short8*)(gA + (KO));                                       \
    S##a1 = *(const short8*)(gA + (KO) + 512);                                 \
    S##a2 = *(const short8*)(gA + (KO) + 1024);                                \
    S##a3 = *(const short8*)(gA + (KO) + 1536);                                \
    S##b0 = *(const short8*)(gB + (KO));                                       \
    S##b1 = *(const short8*)(gB + (KO) + 512);                                 \
    S##b2 = *(const short8*)(gB + (KO) + 1024);                                \
    S##b3 = *(const short8*)(gB + (KO) + 1536);                                \
    S##b4 = *(const short8*)(gB + (KO) + 2048);                                \
    S##b5 = *(const short8*)(gB + (KO) + 2560);                                \
    S##b6 = *(const short8*)(gB + (KO) + 3072);                                \
    S##b7 = *(const short8*)(gB + (KO) + 3584);                                \
  } while (0)

#define MF8(AF, MI, S)                                                                       \
  acc[MI][0] = __builtin_amdgcn_mfma_f32_16x16x32_bf16(AF, S##b0, acc[MI][0], 0, 0, 0);      \
  acc[MI][1] = __builtin_amdgcn_mfma_f32_16x16x32_bf16(AF, S##b1, acc[MI][1], 0, 0, 0);      \
  acc[MI][2] = __builtin_amdgcn_mfma_f32_16x16x32_bf16(AF, S##b2, acc[MI][2], 0, 0, 0);      \
  acc[MI][3] = __builtin_amdgcn_mfma_f32_16x16x32_bf16(AF, S##b3, acc[MI][3], 0, 0, 0);      \
  acc[MI][4] = __builtin_amdgcn_mfma_f32_16x16x32_bf16(AF, S##b4, acc[MI][4], 0, 0, 0);      \
  acc[MI][5] = __builtin_amdgcn_mfma_f32_16x16x32_bf16(AF, S##b5, acc[MI][5], 0, 0, 0);      \
  acc[MI][6] = __builtin_amdgcn_mfma_f32_16x16x32_bf16(AF, S##b6, acc[MI][6], 0, 0, 0);      \
  acc[MI][7] = __builtin_amdgcn_mfma_f32_16x16x32_bf16(AF, S##b7, acc[MI][7], 0, 0, 0);

#define MFALL(S)                                                               \
  __builtin_amdgcn_s_setprio(1);                                               \
  MF8(S##a0, 0, S) MF8(S##a1, 1, S) MF8(S##a2, 2, S) MF8(S##a3, 3, S)          \
  __builtin_amdgcn_s_setprio(0);

  // prologue: load window 0 into p
  LOADSET(p, 0);
  // main: 31 iterations x 2 windows; window 2i consumes p (prefetch q=2i+1),
  // window 2i+1 consumes q (prefetch p=2i+2).
  for (int i = 0; i < 31; ++i) {
    LOADSET(q, 8192);
    MFALL(p)
    LOADSET(p, 16384);
    MFALL(q)
    gA += 16384; gB += 16384;
  }
  // windows 62 (in p), 63
  LOADSET(q, 8192);
  MFALL(p)
  MFALL(q)
#undef MFALL
#undef MF8
#undef LOADSET

  // ---- fused LSTM epilogue ----
  // Wave N-span = 128 cols = two u-16-blocks; gate = ni&3, ublock = ni>>2.
  // C/D layout: col = lane&15, row = (lane>>4)*4 + j.
  int mbase = bm * 256 + wm * 64;
  int nbase = bn * 256 + wn * 128;
  int ub = nbase >> 2;
  int u0 = ub + rl;
  int u1 = ub + 16 + rl;
  float bi0 = b_i[u0], bf0 = b_f[u0], bc0 = b_c[u0], bo0 = b_o[u0];
  float bi1 = b_i[u1], bf1 = b_f[u1], bc1 = b_c[u1], bo1 = b_o[u1];
  int rquad = kg << 2;
#pragma unroll
  for (int mi = 0; mi < 4; ++mi) {
#pragma unroll
    for (int j = 0; j < 4; ++j) {
      int brow = mbase + mi * 16 + rquad + j;
      {
        float zi = acc[mi][0][j] + bi0;
        float zf = acc[mi][1][j] + bf0;
        float zc = acc[mi][2][j] + bc0;
        float zo = acc[mi][3][j] + bo0;
        float ig = sigmoidf_fast(zi);
        float fg = sigmoidf_fast(zf);
        float cg = tanhf_fast(zc);
        float og = sigmoidf_fast(zo);
        float cp = c_tm1[(long)brow * 1024 + u0];
        float cn = fg * cp + ig * cg;
        float hn = og * tanhf_fast(cn);
        outH[(long)brow * 1024 + u0] = hn;
        outC[(long)brow * 1024 + u0] = cn;
      }
      {
        float zi = acc[mi][4][j] + bi1;
        float zf = acc[mi][5][j] + bf1;
        float zc = acc[mi][6][j] + bc1;
        float zo = acc[mi][7][j] + bo1;
        float ig = sigmoidf_fast(zi);
        float fg = sigmoidf_fast(zf);
        float cg = tanhf_fast(zc);
        float og = sigmoidf_fast(zo);
        float cp = c_tm1[(long)brow * 1024 + u1];
        float cn = fg * cp + ig * cg;
        float hn = og * tanhf_fast(cn);
        outH[(long)brow * 1024 + u1] = hn;
        outC[(long)brow * 1024 + u1] = cn;
      }
    }
  }
}

extern "C" void kernel_launch(void* const* d_in, const int* in_sizes, int n_in,
                              void* d_out, int out_size, void* d_ws, size_t ws_size,
                              hipStream_t stream) {
  (void)in_sizes; (void)n_in; (void)out_size; (void)ws_size;
  const float* X   = (const float*)d_in[0];
  const float* Hst = (const float*)d_in[1];
  const float* Cst = (const float*)d_in[2];
  const float* W_i = (const float*)d_in[3];
  const float* U_i = (const float*)d_in[4];
  const float* b_i = (const float*)d_in[5];
  const float* W_f = (const float*)d_in[6];
  const float* U_f = (const float*)d_in[7];
  const float* b_f = (const float*)d_in[8];
  const float* W_c = (const float*)d_in[9];
  const float* U_c = (const float*)d_in[10];
  const float* b_c = (const float*)d_in[11];
  const float* W_o = (const float*)d_in[12];
  const float* U_o = (const float*)d_in[13];
  const float* b_o = (const float*)d_in[14];

  unsigned short* Ap = (unsigned short*)d_ws;                        // 32 MB, frag-major
  unsigned short* Bp = (unsigned short*)((char*)d_ws + 33554432);    // 16 MB, frag-major

  float* outH = (float*)d_out;
  float* outC = outH + 8192L * 1024;

  conv_a_kernel<<<dim3(64, 32), 256, 0, stream>>>(X, Hst, Ap);
  conv_b_kernel<<<dim3(16, 16, 8), 256, 0, stream>>>(W_i, U_i, W_f, U_f, W_c, U_c, W_o, U_o, Bp);
  lstm_gemm_kernel<<<512, 512, 0, stream>>>(Ap, Bp, b_i, b_f, b_c, b_o, Cst, outH, outC);
}